// Round 2
// baseline (414.311 us; speedup 1.0000x reference)
//
#include <hip/hip_runtime.h>
#include <math.h>

// Problem constants
#define B_   32
#define CD   1280     // C
#define HW_  1024
#define TD_  768
#define LD_  64
#define EPSF 1e-5f
#define LORA_SCALE_F 0.125f   // 64^-0.5
#define NROWS (B_ * HW_)      // 32768

// ---------- reduction helpers ----------
__device__ __forceinline__ float wredSum(float a) {
#pragma unroll
  for (int o = 32; o; o >>= 1) a += __shfl_xor(a, o, 64);
  return a;
}
__device__ __forceinline__ void wred2(float& a, float& b) {
#pragma unroll
  for (int o = 32; o; o >>= 1) { a += __shfl_xor(a, o, 64); b += __shfl_xor(b, o, 64); }
}
// block of 256 threads
__device__ __forceinline__ float blockSum(float v, float* red) {
  int t = threadIdx.x;
  red[t] = v; __syncthreads();
#pragma unroll
  for (int s = 128; s > 0; s >>= 1) { if (t < s) red[t] += red[t + s]; __syncthreads(); }
  float r = red[0]; __syncthreads();
  return r;
}
__device__ __forceinline__ float blockMax(float v, float* red) {
  int t = threadIdx.x;
  red[t] = v; __syncthreads();
#pragma unroll
  for (int s = 128; s > 0; s >>= 1) { if (t < s) red[t] = fmaxf(red[t], red[t + s]); __syncthreads(); }
  float r = red[0]; __syncthreads();
  return r;
}
__device__ __forceinline__ void blockSum2(float& a, float& b, float2* red) {
  int t = threadIdx.x;
  red[t] = make_float2(a, b); __syncthreads();
#pragma unroll
  for (int s = 128; s > 0; s >>= 1) {
    if (t < s) { red[t].x += red[t + s].x; red[t].y += red[t + s].y; }
    __syncthreads();
  }
  a = red[0].x; b = red[0].y; __syncthreads();
}

// ================================================================
// kAD1: fused launch.
//   blocks [0,320):    A12  -> q[c] = to_q_w[c,:] . (LN(tq)*g+b)
//   blocks [320,2368): D1   -> partial per-(b,j) sums of infeat over a
//                              320-wide c-quarter (4 quarters => 2048 blocks)
// ================================================================
__global__ __launch_bounds__(256) void kAD1(const float* __restrict__ tq,
                                            const float* __restrict__ lng,
                                            const float* __restrict__ lnb,
                                            const float* __restrict__ to_q_w,
                                            const float* __restrict__ infeat,
                                            float* __restrict__ q_out,
                                            float* __restrict__ Spart,
                                            float* __restrict__ Qpart) {
  __shared__ float smem[2048];   // 8 KB, overlaid by both paths
  int t = threadIdx.x;
  if (blockIdx.x < 320) {
    // ---- A12 path ----
    float* lnq = smem;                       // 768 floats
    float2* red = (float2*)(smem + 768);     // 256 float2
    float s = 0.f, ss = 0.f, vals[3];
#pragma unroll
    for (int k = 0; k < 3; k++) { float v = tq[t + 256 * k]; vals[k] = v; s += v; ss += v * v; }
    blockSum2(s, ss, red);
    float mu = s * (1.f / TD_);
    float r = rsqrtf(ss * (1.f / TD_) - mu * mu + EPSF);
#pragma unroll
    for (int k = 0; k < 3; k++) { int i = t + 256 * k; lnq[i] = (vals[k] - mu) * r * lng[i] + lnb[i]; }
    __syncthreads();
    int c = blockIdx.x * 4 + (t >> 6);
    int lane = t & 63;
    const float4* w4 = (const float4*)(to_q_w + (size_t)c * TD_);
    const float4* l4 = (const float4*)lnq;
    float dot = 0.f;
#pragma unroll
    for (int i = 0; i < 3; i++) {
      int f = i * 64 + lane;
      float4 w = w4[f], l = l4[f];
      dot += w.x * l.x + w.y * l.y + w.z * l.z + w.w * l.w;
    }
    dot = wredSum(dot);
    if (lane == 0) q_out[c] = dot;
  } else {
    // ---- D1 path ----
    int idx = blockIdx.x - 320;          // [0, 2048)
    int b = idx >> 6;                    // 32 batches
    int rr = idx & 63;
    int tile = rr >> 2;                  // 16 j-tiles of 64
    int qtr = rr & 3;                    // 4 c-quarters of 320
    int jg = t & 15;                     // 16 float4 groups -> 64 j columns
    int slice = t >> 4;                  // 16 c-slices of 20
    int j0 = tile * 64 + jg * 4;
    const float* base = infeat + (size_t)b * CD * HW_ + j0;
    int c0 = qtr * 320 + slice * 20;
    float4 s = make_float4(0, 0, 0, 0), q = make_float4(0, 0, 0, 0);
#pragma unroll
    for (int c = c0; c < c0 + 20; c++) {
      float4 v = *(const float4*)(base + (size_t)c * HW_);
      s.x += v.x; s.y += v.y; s.z += v.z; s.w += v.w;
      q.x += v.x * v.x; q.y += v.y * v.y; q.z += v.z * v.z; q.w += v.w * v.w;
    }
    float4* sArr = (float4*)smem;            // 16x16 float4
    float4* qArr = (float4*)(smem + 1024);   // 16x16 float4
    sArr[slice * 16 + jg] = s; qArr[slice * 16 + jg] = q;
    __syncthreads();
#pragma unroll
    for (int st = 8; st > 0; st >>= 1) {
      if (slice < st) {
        float4 a = sArr[slice * 16 + jg], b2 = sArr[(slice + st) * 16 + jg];
        a.x += b2.x; a.y += b2.y; a.z += b2.z; a.w += b2.w;
        sArr[slice * 16 + jg] = a;
        a = qArr[slice * 16 + jg]; b2 = qArr[(slice + st) * 16 + jg];
        a.x += b2.x; a.y += b2.y; a.z += b2.z; a.w += b2.w;
        qArr[slice * 16 + jg] = a;
      }
      __syncthreads();
    }
    if (slice == 0) {
      size_t o = ((size_t)(b * 4 + qtr) << 10) + j0;
      *(float4*)(Spart + o) = sArr[jg];
      *(float4*)(Qpart + o) = qArr[jg];
    }
  }
}

// ================================================================
// kPrep: single block, 1024 threads.
//  LN(q) -> lora_q (64 dots) -> w_eff -> per-c coeff (g2, gb, wg, g)
//  + 8 scalar sums: Sg, Sg2, Sgb, Sb, Sb2, Swg, Swb, W0
// ================================================================
__global__ __launch_bounds__(1024) void kPrep(const float* __restrict__ q_in,
                                              const float* __restrict__ lora_q_w,
                                              const float* __restrict__ lora_k_w,
                                              const float* __restrict__ kg,
                                              const float* __restrict__ kb,
                                              float4* __restrict__ coeff,
                                              float* __restrict__ scalars) {
  __shared__ float qn[CD];
  __shared__ float lqs[LD_];
  __shared__ float4 red4[1024];
  int t = threadIdx.x;
  // LN(q), no affine
  float v0 = q_in[t];
  float v1 = (t < CD - 1024) ? q_in[1024 + t] : 0.f;
  red4[t] = make_float4(v0 + v1, v0 * v0 + v1 * v1, 0.f, 0.f);
  __syncthreads();
#pragma unroll
  for (int st = 512; st > 0; st >>= 1) {
    if (t < st) { red4[t].x += red4[t + st].x; red4[t].y += red4[t + st].y; }
    __syncthreads();
  }
  float mu = red4[0].x * (1.f / CD);
  float r = rsqrtf(red4[0].y * (1.f / CD) - mu * mu + EPSF);
  __syncthreads();
  qn[t] = (v0 - mu) * r;
  if (t < CD - 1024) qn[1024 + t] = (v1 - mu) * r;
  __syncthreads();
  // lora_q[d] = LN(q) . lora_q_w[d,:]; wave w handles d = 4w..4w+3
  int w = t >> 6, lane = t & 63;
  int d0 = w * 4;
  const float4* qn4 = (const float4*)qn;
  float dacc[4] = {0.f, 0.f, 0.f, 0.f};
#pragma unroll
  for (int i = 0; i < 5; i++) {
    int f = i * 64 + lane;
    float4 qv = qn4[f];
#pragma unroll
    for (int dd = 0; dd < 4; dd++) {
      float4 wv = *(const float4*)(lora_q_w + (size_t)(d0 + dd) * CD + 4 * f);
      dacc[dd] += wv.x * qv.x + wv.y * qv.y + wv.z * qv.z + wv.w * qv.w;
    }
  }
#pragma unroll
  for (int o = 32; o; o >>= 1) {
#pragma unroll
    for (int dd = 0; dd < 4; dd++) dacc[dd] += __shfl_xor(dacc[dd], o, 64);
  }
  if (lane == 0) {
#pragma unroll
    for (int dd = 0; dd < 4; dd++) lqs[d0 + dd] = dacc[dd];
  }
  __syncthreads();
  // w_eff + coeff + scalar partials
  float4 pA = make_float4(0, 0, 0, 0);  // Sg, Sg2, Sgb, Sb
  float4 pB = make_float4(0, 0, 0, 0);  // Sb2, Swg, Swb, W0
#pragma unroll
  for (int pass = 0; pass < 2; pass++) {
    int c = (pass == 0) ? t : 1024 + t;
    if (pass == 0 || t < CD - 1024) {
      float acc = 0.f;
#pragma unroll 16
      for (int d = 0; d < LD_; d++) acc += lqs[d] * lora_k_w[(size_t)d * CD + c];
      float g = kg[c], b = kb[c], wv = acc;
      coeff[c] = make_float4(g * g, g * b, wv * g, g);
      pA.x += g; pA.y += g * g; pA.z += g * b; pA.w += b;
      pB.x += b * b; pB.y += wv * g; pB.z += wv * b; pB.w += wv;
    }
  }
  red4[t] = pA; __syncthreads();
#pragma unroll
  for (int st = 512; st > 0; st >>= 1) {
    if (t < st) {
      red4[t].x += red4[t + st].x; red4[t].y += red4[t + st].y;
      red4[t].z += red4[t + st].z; red4[t].w += red4[t + st].w;
    }
    __syncthreads();
  }
  if (t == 0) {
    scalars[0] = red4[0].x; scalars[1] = red4[0].y;
    scalars[2] = red4[0].z; scalars[3] = red4[0].w;
  }
  __syncthreads();
  red4[t] = pB; __syncthreads();
#pragma unroll
  for (int st = 512; st > 0; st >>= 1) {
    if (t < st) {
      red4[t].x += red4[t + st].x; red4[t].y += red4[t + st].y;
      red4[t].z += red4[t + st].z; red4[t].w += red4[t + st].w;
    }
    __syncthreads();
  }
  if (t == 0) {
    scalars[4] = red4[0].x; scalars[5] = red4[0].y;
    scalars[6] = red4[0].z; scalars[7] = red4[0].w;
  }
}

// ================================================================
// kB: sim[row] for all 32768 rows. Single pass over x with 7 running
// sums; LN2 + dot recovered algebraically. Coefficients register-cached.
// ================================================================
__global__ __launch_bounds__(256) void kB(const float* __restrict__ kin,
                                          const float4* __restrict__ coeff,
                                          const float* __restrict__ scalars,
                                          float* __restrict__ sim) {
  int t = threadIdx.x, wid = t >> 6, lane = t & 63;
  // register-cache coefficients for this lane's 20 channels
  float4 cf[20];
#pragma unroll
  for (int i = 0; i < 5; i++) {
    int f = i * 64 + lane;
#pragma unroll
    for (int k = 0; k < 4; k++) cf[i * 4 + k] = coeff[f * 4 + k];
  }
  float Sg = scalars[0], Sg2 = scalars[1], Sgb = scalars[2], Sb = scalars[3];
  float Sb2 = scalars[4], Swg = scalars[5], Swb = scalars[6], W0 = scalars[7];
  int row0 = blockIdx.x * 4 + wid;
  for (int row = row0; row < NROWS; row += 8192) {
    const float4* x4 = (const float4*)(kin + (size_t)row * CD);
    float sx = 0.f, sxx = 0.f, sA = 0.f, sB = 0.f, sC = 0.f, sD = 0.f, sE = 0.f;
#pragma unroll
    for (int i = 0; i < 5; i++) {
      float4 v = x4[i * 64 + lane];
      float xs[4] = {v.x, v.y, v.z, v.w};
#pragma unroll
      for (int k = 0; k < 4; k++) {
        float x = xs[k];
        float4 c = cf[i * 4 + k];   // (g2, gb, wg, g)
        float xx = x * x;
        sx += x; sxx += xx;
        sA += c.x * xx; sB += c.x * x; sC += c.y * x; sD += c.z * x; sE += c.w * x;
      }
    }
#pragma unroll
    for (int o = 32; o; o >>= 1) {
      sx += __shfl_xor(sx, o, 64);  sxx += __shfl_xor(sxx, o, 64);
      sA += __shfl_xor(sA, o, 64);  sB += __shfl_xor(sB, o, 64);
      sC += __shfl_xor(sC, o, 64);  sD += __shfl_xor(sD, o, 64);
      sE += __shfl_xor(sE, o, 64);
    }
    float mu1 = sx * (1.f / CD);
    float r1 = rsqrtf(sxx * (1.f / CD) - mu1 * mu1 + EPSF);
    float Sk = r1 * (sE - mu1 * Sg) + Sb;
    float Sk2 = r1 * r1 * (sA - 2.f * mu1 * sB + mu1 * mu1 * Sg2)
              + 2.f * r1 * (sC - mu1 * Sgb) + Sb2;
    float Swk = r1 * (sD - mu1 * Swg) + Swb;
    float mu2 = Sk * (1.f / CD);
    float r2 = rsqrtf(Sk2 * (1.f / CD) - mu2 * mu2 + EPSF);
    if (lane == 0) sim[row] = LORA_SCALE_F * r2 * (Swk - mu2 * W0);
  }
}

// ================================================================
// kCD2: per-block softmax prologue (redundant per tile) + weighted
// row dots over infeat -> out[b, 2C]. grid = 32 b x 40 tiles.
// ================================================================
__global__ __launch_bounds__(256) void kCD2(const float* __restrict__ infeat,
                                            const float* __restrict__ sim,
                                            const float* __restrict__ mask,
                                            const float* __restrict__ Spart,
                                            const float* __restrict__ Qpart,
                                            const float* __restrict__ g,
                                            const float* __restrict__ bb,
                                            float* __restrict__ out) {
  __shared__ float4 w1s[HW_ / 4], w2s[HW_ / 4];
  __shared__ float red[256];
  __shared__ float2 red2[256];
  int t = threadIdx.x;
  int b = blockIdx.x / 40, tile = blockIdx.x % 40;
  // ---- prologue: finalize stats + softmax -> w1, w2, S1, S3 ----
  float4 S = make_float4(0, 0, 0, 0), Q = make_float4(0, 0, 0, 0);
#pragma unroll
  for (int q = 0; q < 4; q++) {
    size_t o = ((size_t)(b * 4 + q) << 10);
    float4 sp = ((const float4*)(Spart + o))[t];
    float4 qp = ((const float4*)(Qpart + o))[t];
    S.x += sp.x; S.y += sp.y; S.z += sp.z; S.w += sp.w;
    Q.x += qp.x; Q.y += qp.y; Q.z += qp.z; Q.w += qp.w;
  }
  float4 muv, rv;
  muv.x = S.x * (1.f / CD); muv.y = S.y * (1.f / CD);
  muv.z = S.z * (1.f / CD); muv.w = S.w * (1.f / CD);
  rv.x = rsqrtf(Q.x * (1.f / CD) - muv.x * muv.x + EPSF);
  rv.y = rsqrtf(Q.y * (1.f / CD) - muv.y * muv.y + EPSF);
  rv.z = rsqrtf(Q.z * (1.f / CD) - muv.z * muv.z + EPSF);
  rv.w = rsqrtf(Q.w * (1.f / CD) - muv.w * muv.w + EPSF);
  float4 sv = ((const float4*)(sim + b * HW_))[t];
  float4 mv = ((const float4*)(mask + b * HW_))[t];
  const float NEG = -3.4028235e38f;
  float se0 = mv.x > 0.f ? sv.x : NEG;
  float se1 = mv.y > 0.f ? sv.y : NEG;
  float se2 = mv.z > 0.f ? sv.z : NEG;
  float se3 = mv.w > 0.f ? sv.w : NEG;
  float M = blockMax(fmaxf(fmaxf(se0, se1), fmaxf(se2, se3)), red);
  float e0 = expf(se0 - M), e1 = expf(se1 - M), e2 = expf(se2 - M), e3 = expf(se3 - M);
  float Z = blockSum(e0 + e1 + e2 + e3, red);
  float inv = 1.f / Z;
  float4 w1v = make_float4(e0 * inv * rv.x, e1 * inv * rv.y, e2 * inv * rv.z, e3 * inv * rv.w);
  float4 w2v = make_float4(rv.x * (1.f / HW_), rv.y * (1.f / HW_),
                           rv.z * (1.f / HW_), rv.w * (1.f / HW_));
  float s1 = w1v.x * muv.x + w1v.y * muv.y + w1v.z * muv.z + w1v.w * muv.w;
  float s3 = w2v.x * muv.x + w2v.y * muv.y + w2v.z * muv.z + w2v.w * muv.w;
  blockSum2(s1, s3, red2);
  w1s[t] = w1v; w2s[t] = w2v;
  __syncthreads();
  // ---- main: weighted dots over 32 c-rows ----
  int wid = t >> 6, lane = t & 63;
#pragma unroll
  for (int k = 0; k < 8; k++) {
    int c = tile * 32 + wid * 8 + k;
    const float4* x4 = (const float4*)(infeat + (size_t)b * CD * HW_ + (size_t)c * HW_);
    float d1 = 0.f, d2 = 0.f;
#pragma unroll
    for (int i = 0; i < 4; i++) {
      int f = i * 64 + lane;
      float4 x = x4[f], a = w1s[f], w = w2s[f];
      d1 += x.x * a.x + x.y * a.y + x.z * a.z + x.w * a.w;
      d2 += x.x * w.x + x.y * w.y + x.z * w.z + x.w * w.w;
    }
    wred2(d1, d2);
    if (lane == 0) {
      float gc = g[c], bc = bb[c];
      float fg = gc * (d1 - s1) + bc;
      float vm = gc * (d2 - s3) + bc;
      out[(size_t)b * (2 * CD) + c] = fg;
      out[(size_t)b * (2 * CD) + CD + c] = vm - fg;
    }
  }
}

extern "C" void kernel_launch(void* const* d_in, const int* in_sizes, int n_in,
                              void* d_out, int out_size, void* d_ws, size_t ws_size,
                              hipStream_t stream) {
  const float* infeat  = (const float*)d_in[0];
  const float* inquery = (const float*)d_in[1];
  const float* tq      = (const float*)d_in[2];
  const float* to_q_w  = (const float*)d_in[3];
  const float* ln_x_g  = (const float*)d_in[4];
  const float* ln_x_b  = (const float*)d_in[5];
  const float* ln_k_g  = (const float*)d_in[6];
  const float* ln_k_b  = (const float*)d_in[7];
  const float* ln_q_g  = (const float*)d_in[8];
  const float* ln_q_b  = (const float*)d_in[9];
  const float* lora_q_w = (const float*)d_in[10];
  const float* lora_k_w = (const float*)d_in[11];
  const float* mask    = (const float*)d_in[12];
  float* out = (float*)d_out;

  float* ws = (float*)d_ws;
  float* q_ws      = ws;                 // 1280
  float* coeff_ws  = ws + 1280;          // 5120 (1280 float4)
  float* scal_ws   = ws + 6400;          // 8
  float* sim_ws    = ws + 6408;          // 32768
  float* Spart_ws  = ws + 39176;         // 131072
  float* Qpart_ws  = ws + 170248;        // 131072  (end 301320)

  kAD1<<<2368, 256, 0, stream>>>(tq, ln_q_g, ln_q_b, to_q_w, infeat,
                                 q_ws, Spart_ws, Qpart_ws);
  kPrep<<<1, 1024, 0, stream>>>(q_ws, lora_q_w, lora_k_w, ln_k_g, ln_k_b,
                                (float4*)coeff_ws, scal_ws);
  kB<<<2048, 256, 0, stream>>>(inquery, (const float4*)coeff_ws, scal_ws, sim_ws);
  kCD2<<<1280, 256, 0, stream>>>(infeat, sim_ws, mask, Spart_ws, Qpart_ws,
                                 ln_x_g, ln_x_b, out);
}

// Round 3
// 412.875 us; speedup vs baseline: 1.0035x; 1.0035x over previous
//
#include <hip/hip_runtime.h>
#include <math.h>

// Problem constants
#define B_   32
#define CD   1280     // C
#define HW_  1024
#define TD_  768
#define LD_  64
#define EPSF 1e-5f
#define LORA_SCALE_F 0.125f   // 64^-0.5
#define NROWS (B_ * HW_)      // 32768

// ---------- reduction helpers ----------
__device__ __forceinline__ float wredSum(float a) {
#pragma unroll
  for (int o = 32; o; o >>= 1) a += __shfl_xor(a, o, 64);
  return a;
}
__device__ __forceinline__ void wred2(float& a, float& b) {
#pragma unroll
  for (int o = 32; o; o >>= 1) { a += __shfl_xor(a, o, 64); b += __shfl_xor(b, o, 64); }
}
// block of 256 threads
__device__ __forceinline__ float blockSum(float v, float* red) {
  int t = threadIdx.x;
  red[t] = v; __syncthreads();
#pragma unroll
  for (int s = 128; s > 0; s >>= 1) { if (t < s) red[t] += red[t + s]; __syncthreads(); }
  float r = red[0]; __syncthreads();
  return r;
}
__device__ __forceinline__ float blockMax(float v, float* red) {
  int t = threadIdx.x;
  red[t] = v; __syncthreads();
#pragma unroll
  for (int s = 128; s > 0; s >>= 1) { if (t < s) red[t] = fmaxf(red[t], red[t + s]); __syncthreads(); }
  float r = red[0]; __syncthreads();
  return r;
}
__device__ __forceinline__ void blockSum2(float& a, float& b, float2* red) {
  int t = threadIdx.x;
  red[t] = make_float2(a, b); __syncthreads();
#pragma unroll
  for (int s = 128; s > 0; s >>= 1) {
    if (t < s) { red[t].x += red[t + s].x; red[t].y += red[t + s].y; }
    __syncthreads();
  }
  a = red[0].x; b = red[0].y; __syncthreads();
}

// ================================================================
// kA12: q[c] = to_q_w[c,:] . (LN(tq)*g+b) ; grid 320x256
// ================================================================
__global__ __launch_bounds__(256) void kA12(const float* __restrict__ tq,
                                            const float* __restrict__ lng,
                                            const float* __restrict__ lnb,
                                            const float* __restrict__ to_q_w,
                                            float* __restrict__ q_out) {
  __shared__ float lnq[TD_];
  __shared__ float2 red[256];
  int t = threadIdx.x;
  float s = 0.f, ss = 0.f, vals[3];
#pragma unroll
  for (int k = 0; k < 3; k++) { float v = tq[t + 256 * k]; vals[k] = v; s += v; ss += v * v; }
  blockSum2(s, ss, red);
  float mu = s * (1.f / TD_);
  float r = rsqrtf(ss * (1.f / TD_) - mu * mu + EPSF);
#pragma unroll
  for (int k = 0; k < 3; k++) { int i = t + 256 * k; lnq[i] = (vals[k] - mu) * r * lng[i] + lnb[i]; }
  __syncthreads();
  int c = blockIdx.x * 4 + (t >> 6);
  int lane = t & 63;
  const float4* w4 = (const float4*)(to_q_w + (size_t)c * TD_);
  const float4* l4 = (const float4*)lnq;
  float dot = 0.f;
#pragma unroll
  for (int i = 0; i < 3; i++) {
    int f = i * 64 + lane;
    float4 w = w4[f], l = l4[f];
    dot += w.x * l.x + w.y * l.y + w.z * l.z + w.w * l.w;
  }
  dot = wredSum(dot);
  if (lane == 0) q_out[c] = dot;
}

// ================================================================
// kD1: per-(b,j) partial stats of infeat over a 320-wide c-quarter.
// grid 2048x256 (32 b x 16 j-tiles x 4 c-quarters)
// ================================================================
__global__ __launch_bounds__(256) void kD1(const float* __restrict__ infeat,
                                           float* __restrict__ Spart,
                                           float* __restrict__ Qpart) {
  __shared__ float smem[2048];
  int t = threadIdx.x;
  int idx = blockIdx.x;                // [0, 2048)
  int b = idx >> 6;                    // 32 batches
  int rr = idx & 63;
  int tile = rr >> 2;                  // 16 j-tiles of 64
  int qtr = rr & 3;                    // 4 c-quarters of 320
  int jg = t & 15;                     // 16 float4 groups -> 64 j columns
  int slice = t >> 4;                  // 16 c-slices of 20
  int j0 = tile * 64 + jg * 4;
  const float* base = infeat + (size_t)b * CD * HW_ + j0;
  int c0 = qtr * 320 + slice * 20;
  float4 s = make_float4(0, 0, 0, 0), q = make_float4(0, 0, 0, 0);
#pragma unroll
  for (int c = c0; c < c0 + 20; c++) {
    float4 v = *(const float4*)(base + (size_t)c * HW_);
    s.x += v.x; s.y += v.y; s.z += v.z; s.w += v.w;
    q.x += v.x * v.x; q.y += v.y * v.y; q.z += v.z * v.z; q.w += v.w * v.w;
  }
  float4* sArr = (float4*)smem;            // 16x16 float4
  float4* qArr = (float4*)(smem + 1024);   // 16x16 float4
  sArr[slice * 16 + jg] = s; qArr[slice * 16 + jg] = q;
  __syncthreads();
#pragma unroll
  for (int st = 8; st > 0; st >>= 1) {
    if (slice < st) {
      float4 a = sArr[slice * 16 + jg], b2 = sArr[(slice + st) * 16 + jg];
      a.x += b2.x; a.y += b2.y; a.z += b2.z; a.w += b2.w;
      sArr[slice * 16 + jg] = a;
      a = qArr[slice * 16 + jg]; b2 = qArr[(slice + st) * 16 + jg];
      a.x += b2.x; a.y += b2.y; a.z += b2.z; a.w += b2.w;
      qArr[slice * 16 + jg] = a;
    }
    __syncthreads();
  }
  if (slice == 0) {
    size_t o = ((size_t)(b * 4 + qtr) << 10) + j0;
    *(float4*)(Spart + o) = sArr[jg];
    *(float4*)(Qpart + o) = qArr[jg];
  }
}

// ================================================================
// kPrep: single block, 1024 threads.
//  LN(q) -> lora_q (64 dots) -> w_eff -> per-c coeff (g2, gb, wg, g)
//  + 8 scalar sums: Sg, Sg2, Sgb, Sb, Sb2, Swg, Swb, W0
// ================================================================
__global__ __launch_bounds__(1024) void kPrep(const float* __restrict__ q_in,
                                              const float* __restrict__ lora_q_w,
                                              const float* __restrict__ lora_k_w,
                                              const float* __restrict__ kg,
                                              const float* __restrict__ kb,
                                              float4* __restrict__ coeff,
                                              float* __restrict__ scalars) {
  __shared__ float qn[CD];
  __shared__ float lqs[LD_];
  __shared__ float4 red4[1024];
  int t = threadIdx.x;
  // LN(q), no affine
  float v0 = q_in[t];
  float v1 = (t < CD - 1024) ? q_in[1024 + t] : 0.f;
  red4[t] = make_float4(v0 + v1, v0 * v0 + v1 * v1, 0.f, 0.f);
  __syncthreads();
#pragma unroll
  for (int st = 512; st > 0; st >>= 1) {
    if (t < st) { red4[t].x += red4[t + st].x; red4[t].y += red4[t + st].y; }
    __syncthreads();
  }
  float mu = red4[0].x * (1.f / CD);
  float r = rsqrtf(red4[0].y * (1.f / CD) - mu * mu + EPSF);
  __syncthreads();
  qn[t] = (v0 - mu) * r;
  if (t < CD - 1024) qn[1024 + t] = (v1 - mu) * r;
  __syncthreads();
  // lora_q[d] = LN(q) . lora_q_w[d,:]; wave w handles d = 4w..4w+3
  int w = t >> 6, lane = t & 63;
  int d0 = w * 4;
  const float4* qn4 = (const float4*)qn;
  float dacc[4] = {0.f, 0.f, 0.f, 0.f};
#pragma unroll
  for (int i = 0; i < 5; i++) {
    int f = i * 64 + lane;
    float4 qv = qn4[f];
#pragma unroll
    for (int dd = 0; dd < 4; dd++) {
      float4 wv = *(const float4*)(lora_q_w + (size_t)(d0 + dd) * CD + 4 * f);
      dacc[dd] += wv.x * qv.x + wv.y * qv.y + wv.z * qv.z + wv.w * qv.w;
    }
  }
#pragma unroll
  for (int o = 32; o; o >>= 1) {
#pragma unroll
    for (int dd = 0; dd < 4; dd++) dacc[dd] += __shfl_xor(dacc[dd], o, 64);
  }
  if (lane == 0) {
#pragma unroll
    for (int dd = 0; dd < 4; dd++) lqs[d0 + dd] = dacc[dd];
  }
  __syncthreads();
  // w_eff + coeff + scalar partials
  float4 pA = make_float4(0, 0, 0, 0);  // Sg, Sg2, Sgb, Sb
  float4 pB = make_float4(0, 0, 0, 0);  // Sb2, Swg, Swb, W0
#pragma unroll
  for (int pass = 0; pass < 2; pass++) {
    int c = (pass == 0) ? t : 1024 + t;
    if (pass == 0 || t < CD - 1024) {
      float acc = 0.f;
#pragma unroll 16
      for (int d = 0; d < LD_; d++) acc += lqs[d] * lora_k_w[(size_t)d * CD + c];
      float g = kg[c], b = kb[c], wv = acc;
      coeff[c] = make_float4(g * g, g * b, wv * g, g);
      pA.x += g; pA.y += g * g; pA.z += g * b; pA.w += b;
      pB.x += b * b; pB.y += wv * g; pB.z += wv * b; pB.w += wv;
    }
  }
  red4[t] = pA; __syncthreads();
#pragma unroll
  for (int st = 512; st > 0; st >>= 1) {
    if (t < st) {
      red4[t].x += red4[t + st].x; red4[t].y += red4[t + st].y;
      red4[t].z += red4[t + st].z; red4[t].w += red4[t + st].w;
    }
    __syncthreads();
  }
  if (t == 0) {
    scalars[0] = red4[0].x; scalars[1] = red4[0].y;
    scalars[2] = red4[0].z; scalars[3] = red4[0].w;
  }
  __syncthreads();
  red4[t] = pB; __syncthreads();
#pragma unroll
  for (int st = 512; st > 0; st >>= 1) {
    if (t < st) {
      red4[t].x += red4[t + st].x; red4[t].y += red4[t + st].y;
      red4[t].z += red4[t + st].z; red4[t].w += red4[t + st].w;
    }
    __syncthreads();
  }
  if (t == 0) {
    scalars[4] = red4[0].x; scalars[5] = red4[0].y;
    scalars[6] = red4[0].z; scalars[7] = red4[0].w;
  }
}

// ================================================================
// kB: sim[row] for all 32768 rows. Single pass over x with 7 running
// sums; LN2 + dot recovered algebraically. Coefficients register-cached.
// ================================================================
__global__ __launch_bounds__(256) void kB(const float* __restrict__ kin,
                                          const float4* __restrict__ coeff,
                                          const float* __restrict__ scalars,
                                          float* __restrict__ sim) {
  int t = threadIdx.x, wid = t >> 6, lane = t & 63;
  // register-cache coefficients for this lane's 20 channels
  float4 cf[20];
#pragma unroll
  for (int i = 0; i < 5; i++) {
    int f = i * 64 + lane;
#pragma unroll
    for (int k = 0; k < 4; k++) cf[i * 4 + k] = coeff[f * 4 + k];
  }
  float Sg = scalars[0], Sg2 = scalars[1], Sgb = scalars[2], Sb = scalars[3];
  float Sb2 = scalars[4], Swg = scalars[5], Swb = scalars[6], W0 = scalars[7];
  int row0 = blockIdx.x * 4 + wid;
  for (int row = row0; row < NROWS; row += 8192) {
    const float4* x4 = (const float4*)(kin + (size_t)row * CD);
    float sx = 0.f, sxx = 0.f, sA = 0.f, sB = 0.f, sC = 0.f, sD = 0.f, sE = 0.f;
#pragma unroll
    for (int i = 0; i < 5; i++) {
      float4 v = x4[i * 64 + lane];
      float xs[4] = {v.x, v.y, v.z, v.w};
#pragma unroll
      for (int k = 0; k < 4; k++) {
        float x = xs[k];
        float4 c = cf[i * 4 + k];   // (g2, gb, wg, g)
        float xx = x * x;
        sx += x; sxx += xx;
        sA += c.x * xx; sB += c.x * x; sC += c.y * x; sD += c.z * x; sE += c.w * x;
      }
    }
#pragma unroll
    for (int o = 32; o; o >>= 1) {
      sx += __shfl_xor(sx, o, 64);  sxx += __shfl_xor(sxx, o, 64);
      sA += __shfl_xor(sA, o, 64);  sB += __shfl_xor(sB, o, 64);
      sC += __shfl_xor(sC, o, 64);  sD += __shfl_xor(sD, o, 64);
      sE += __shfl_xor(sE, o, 64);
    }
    float mu1 = sx * (1.f / CD);
    float r1 = rsqrtf(sxx * (1.f / CD) - mu1 * mu1 + EPSF);
    float Sk = r1 * (sE - mu1 * Sg) + Sb;
    float Sk2 = r1 * r1 * (sA - 2.f * mu1 * sB + mu1 * mu1 * Sg2)
              + 2.f * r1 * (sC - mu1 * Sgb) + Sb2;
    float Swk = r1 * (sD - mu1 * Swg) + Swb;
    float mu2 = Sk * (1.f / CD);
    float r2 = rsqrtf(Sk2 * (1.f / CD) - mu2 * mu2 + EPSF);
    if (lane == 0) sim[row] = LORA_SCALE_F * r2 * (Swk - mu2 * W0);
  }
}

// ================================================================
// kCD2: per-block softmax prologue (redundant per tile) + weighted
// row dots over infeat -> out[b, 2C]. grid = 32 b x 40 tiles.
// Runs immediately after kD1 so infeat is Infinity-Cache resident.
// ================================================================
__global__ __launch_bounds__(256) void kCD2(const float* __restrict__ infeat,
                                            const float* __restrict__ sim,
                                            const float* __restrict__ mask,
                                            const float* __restrict__ Spart,
                                            const float* __restrict__ Qpart,
                                            const float* __restrict__ g,
                                            const float* __restrict__ bb,
                                            float* __restrict__ out) {
  __shared__ float4 w1s[HW_ / 4], w2s[HW_ / 4];
  __shared__ float red[256];
  __shared__ float2 red2[256];
  int t = threadIdx.x;
  int b = blockIdx.x / 40, tile = blockIdx.x % 40;
  // ---- prologue: finalize stats + softmax -> w1, w2, S1, S3 ----
  float4 S = make_float4(0, 0, 0, 0), Q = make_float4(0, 0, 0, 0);
#pragma unroll
  for (int q = 0; q < 4; q++) {
    size_t o = ((size_t)(b * 4 + q) << 10);
    float4 sp = ((const float4*)(Spart + o))[t];
    float4 qp = ((const float4*)(Qpart + o))[t];
    S.x += sp.x; S.y += sp.y; S.z += sp.z; S.w += sp.w;
    Q.x += qp.x; Q.y += qp.y; Q.z += qp.z; Q.w += qp.w;
  }
  float4 muv, rv;
  muv.x = S.x * (1.f / CD); muv.y = S.y * (1.f / CD);
  muv.z = S.z * (1.f / CD); muv.w = S.w * (1.f / CD);
  rv.x = rsqrtf(Q.x * (1.f / CD) - muv.x * muv.x + EPSF);
  rv.y = rsqrtf(Q.y * (1.f / CD) - muv.y * muv.y + EPSF);
  rv.z = rsqrtf(Q.z * (1.f / CD) - muv.z * muv.z + EPSF);
  rv.w = rsqrtf(Q.w * (1.f / CD) - muv.w * muv.w + EPSF);
  float4 sv = ((const float4*)(sim + b * HW_))[t];
  float4 mv = ((const float4*)(mask + b * HW_))[t];
  const float NEG = -3.4028235e38f;
  float se0 = mv.x > 0.f ? sv.x : NEG;
  float se1 = mv.y > 0.f ? sv.y : NEG;
  float se2 = mv.z > 0.f ? sv.z : NEG;
  float se3 = mv.w > 0.f ? sv.w : NEG;
  float M = blockMax(fmaxf(fmaxf(se0, se1), fmaxf(se2, se3)), red);
  float e0 = expf(se0 - M), e1 = expf(se1 - M), e2 = expf(se2 - M), e3 = expf(se3 - M);
  float Z = blockSum(e0 + e1 + e2 + e3, red);
  float inv = 1.f / Z;
  float4 w1v = make_float4(e0 * inv * rv.x, e1 * inv * rv.y, e2 * inv * rv.z, e3 * inv * rv.w);
  float4 w2v = make_float4(rv.x * (1.f / HW_), rv.y * (1.f / HW_),
                           rv.z * (1.f / HW_), rv.w * (1.f / HW_));
  float s1 = w1v.x * muv.x + w1v.y * muv.y + w1v.z * muv.z + w1v.w * muv.w;
  float s3 = w2v.x * muv.x + w2v.y * muv.y + w2v.z * muv.z + w2v.w * muv.w;
  blockSum2(s1, s3, red2);
  w1s[t] = w1v; w2s[t] = w2v;
  __syncthreads();
  // ---- main: weighted dots over 32 c-rows ----
  int wid = t >> 6, lane = t & 63;
#pragma unroll
  for (int k = 0; k < 8; k++) {
    int c = tile * 32 + wid * 8 + k;
    const float4* x4 = (const float4*)(infeat + (size_t)b * CD * HW_ + (size_t)c * HW_);
    float d1 = 0.f, d2 = 0.f;
#pragma unroll
    for (int i = 0; i < 4; i++) {
      int f = i * 64 + lane;
      float4 x = x4[f], a = w1s[f], w = w2s[f];
      d1 += x.x * a.x + x.y * a.y + x.z * a.z + x.w * a.w;
      d2 += x.x * w.x + x.y * w.y + x.z * w.z + x.w * w.w;
    }
    wred2(d1, d2);
    if (lane == 0) {
      float gc = g[c], bc = bb[c];
      float fg = gc * (d1 - s1) + bc;
      float vm = gc * (d2 - s3) + bc;
      out[(size_t)b * (2 * CD) + c] = fg;
      out[(size_t)b * (2 * CD) + CD + c] = vm - fg;
    }
  }
}

extern "C" void kernel_launch(void* const* d_in, const int* in_sizes, int n_in,
                              void* d_out, int out_size, void* d_ws, size_t ws_size,
                              hipStream_t stream) {
  const float* infeat  = (const float*)d_in[0];
  const float* inquery = (const float*)d_in[1];
  const float* tq      = (const float*)d_in[2];
  const float* to_q_w  = (const float*)d_in[3];
  const float* ln_x_g  = (const float*)d_in[4];
  const float* ln_x_b  = (const float*)d_in[5];
  const float* ln_k_g  = (const float*)d_in[6];
  const float* ln_k_b  = (const float*)d_in[7];
  const float* ln_q_g  = (const float*)d_in[8];
  const float* ln_q_b  = (const float*)d_in[9];
  const float* lora_q_w = (const float*)d_in[10];
  const float* lora_k_w = (const float*)d_in[11];
  const float* mask    = (const float*)d_in[12];
  float* out = (float*)d_out;

  float* ws = (float*)d_ws;
  float* q_ws      = ws;                 // 1280
  float* coeff_ws  = ws + 1280;          // 5120 (1280 float4)
  float* scal_ws   = ws + 6400;          // 8
  float* sim_ws    = ws + 6408;          // 32768
  float* Spart_ws  = ws + 39176;         // 131072
  float* Qpart_ws  = ws + 170248;        // 131072  (end 301320)

  // Order matters: kB's 168 MB inquery stream runs BEFORE the two infeat
  // passes so infeat stays Infinity-Cache resident from kD1 into kCD2.
  kA12<<<320, 256, 0, stream>>>(tq, ln_q_g, ln_q_b, to_q_w, q_ws);
  kPrep<<<1, 1024, 0, stream>>>(q_ws, lora_q_w, lora_k_w, ln_k_g, ln_k_b,
                                (float4*)coeff_ws, scal_ws);
  kB<<<2048, 256, 0, stream>>>(inquery, (const float4*)coeff_ws, scal_ws, sim_ws);
  kD1<<<2048, 256, 0, stream>>>(infeat, Spart_ws, Qpart_ws);
  kCD2<<<1280, 256, 0, stream>>>(infeat, sim_ws, mask, Spart_ws, Qpart_ws,
                                 ln_x_g, ln_x_b, out);
}